// Round 3
// baseline (167.612 us; speedup 1.0000x reference)
//
#include <hip/hip_runtime.h>

#define I_DIM 28
#define H_DIM 64
#define T_DIM 128
#define B_DIM 4096
#define OUT_DIM 10
#define MB 16         // batch rows per block: full 16 MFMA B-columns
#define NTHREADS 512  // 8 waves = 2/SIMD; waves w and w+4 duplicate MFMAs for
                      // h-block (w&3) and split the 4 cells (r 0,1 vs 2,3)
#define LOG2E 1.44269504088896340736f

typedef __attribute__((ext_vector_type(8))) short bf16x8;
typedef __attribute__((ext_vector_type(4))) float f32x4;
typedef __attribute__((ext_vector_type(4))) unsigned u32x4;

__device__ __forceinline__ float bfbits2f(unsigned b16) {
    return __builtin_bit_cast(float, b16 << 16);
}
// rne-rounded fp32 bits (bf16 lives in top 16 after the add)
__device__ __forceinline__ unsigned rne_u(float f) {
    unsigned u = __builtin_bit_cast(unsigned, f);
    return u + 0x7FFFu + ((u >> 16) & 1u);
}
// pack two floats -> (bf16(b)<<16)|bf16(a) : 2 rne-adds + 1 v_perm
__device__ __forceinline__ unsigned pack_pair(float a, float b) {
    return __builtin_amdgcn_perm(rne_u(b), rne_u(a), 0x07060302u);
}
__device__ __forceinline__ unsigned f2bf_rne(float f) { return rne_u(f) >> 16; }
__device__ __forceinline__ unsigned ftrunc_bf(float f) {
    return __builtin_bit_cast(unsigned, f) >> 16;
}

// 8 floats -> single rne-bf16 frag (4 dwords)
__device__ __forceinline__ bf16x8 pack_frag(const float* v) {
    u32x4 w;
    #pragma unroll
    for (int i = 0; i < 4; ++i) w[i] = pack_pair(v[2*i], v[2*i+1]);
    return __builtin_bit_cast(bf16x8, w);
}

// 8 floats -> hi/lo bf16 frags (used for W_ih only; startup)
__device__ __forceinline__ void split_frag(const float* v, bf16x8& hi, bf16x8& lo) {
    unsigned hb[8], lb[8];
    #pragma unroll
    for (int j = 0; j < 8; ++j) {
        hb[j] = f2bf_rne(v[j]);
        float rem = v[j] - bfbits2f(hb[j]);
        lb[j] = ftrunc_bf(rem);
    }
    u32x4 hw, lw;
    #pragma unroll
    for (int i = 0; i < 4; ++i) {
        hw[i] = (hb[2*i+1] << 16) | (hb[2*i] & 0xFFFFu);
        lw[i] = (lb[2*i+1] << 16) | (lb[2*i] & 0xFFFFu);
    }
    hi = __builtin_bit_cast(bf16x8, hw);
    lo = __builtin_bit_cast(bf16x8, lw);
}

__device__ __forceinline__ float fast_rcp(float v) { return __builtin_amdgcn_rcpf(v); }
__device__ __forceinline__ float exp2_f(float v)  { return __builtin_amdgcn_exp2f(v); }
__device__ __forceinline__ float sigmoid_s(float zs) {           // zs = LOG2E*z
    return fast_rcp(1.0f + exp2_f(-zs));
}
__device__ __forceinline__ float tanh_gs(float zs) {             // LOG2E*tanh(z)
    float t = fast_rcp(exp2_f(zs + zs) + 1.0f);
    return fmaf(-2.0f * LOG2E, t, LOG2E);
}
__device__ __forceinline__ float tanh_cs(float cs) {             // tanh(c), cs=LOG2E*c
    float t = fast_rcp(exp2_f(cs + cs) + 1.0f);
    return fmaf(-2.0f, t, 1.0f);
}

#define MFMA(A, B, C) __builtin_amdgcn_mfma_f32_16x16x32_bf16((A), (B), (C), 0, 0, 0)

// Raw barrier with counted wait: LDS writes must be visible (lgkmcnt(0)),
// but global loads (x prefetch) stay in flight across the barrier.
#define BAR() do {                                              \
    asm volatile("s_waitcnt lgkmcnt(0)" ::: "memory");          \
    __builtin_amdgcn_s_barrier();                               \
} while (0)

__global__ __launch_bounds__(NTHREADS, 1)
void lstm_mfma_kernel(const float* __restrict__ x,
                      const float* __restrict__ W_ih,
                      const float* __restrict__ W_hh,
                      const float* __restrict__ b_ih,
                      const float* __restrict__ b_hh,
                      const float* __restrict__ W_out,
                      const float* __restrict__ b_out,
                      float* __restrict__ out)
{
    const int tid  = threadIdx.x;
    const int wv   = tid >> 6;        // wave 0..7
    const int hb   = wv & 3;          // h-block (waves w and w+4 share one)
    const int lane = tid & 63;
    const int q    = lane >> 4;       // quad
    const int cm   = lane & 15;       // batch column (all 16 real)
    const int b0   = blockIdx.x * MB;

    // h state, single rne-bf16, B-frag dword order, double-buffered.
    __shared__ __align__(16) unsigned hbuf[2][512];
    // x B-frags for the chunk's two timesteps (single bf16)
    __shared__ __align__(16) unsigned xbuf[2][256];

    // ---- resident A-frags (weights, pre-scaled by LOG2E):
    bf16x8 Whh[4][2], Wih_hi[4], Wih_lo[4];
    f32x4  bias_c[4];
    #pragma unroll
    for (int g = 0; g < 4; ++g) {
        const int gn = (hb + 4 * g) * 16 + cm;     // global gate row
        #pragma unroll
        for (int kt = 0; kt < 2; ++kt) {
            const float* wr = W_hh + gn * H_DIM + kt * 32 + q * 8;
            float wt[8];
            float4 wa = *(const float4*)wr;
            float4 wb = *(const float4*)(wr + 4);
            wt[0]=wa.x*LOG2E; wt[1]=wa.y*LOG2E; wt[2]=wa.z*LOG2E; wt[3]=wa.w*LOG2E;
            wt[4]=wb.x*LOG2E; wt[5]=wb.y*LOG2E; wt[6]=wb.z*LOG2E; wt[7]=wb.w*LOG2E;
            Whh[g][kt] = pack_frag(wt);
        }
        {
            const float* ir = W_ih + gn * I_DIM + q * 8;
            float wt[8];
            float4 ia = *(const float4*)ir;
            wt[0]=ia.x*LOG2E; wt[1]=ia.y*LOG2E; wt[2]=ia.z*LOG2E; wt[3]=ia.w*LOG2E;
            if (q < 3) {
                float4 ib = *(const float4*)(ir + 4);
                wt[4]=ib.x*LOG2E; wt[5]=ib.y*LOG2E; wt[6]=ib.z*LOG2E; wt[7]=ib.w*LOG2E;
            } else { wt[4]=0.f; wt[5]=0.f; wt[6]=0.f; wt[7]=0.f; }
            split_frag(wt, Wih_hi[g], Wih_lo[g]);
        }
        #pragma unroll
        for (int r = 0; r < 4; ++r) {
            const int row = g * H_DIM + hb * 16 + 4 * q + r;
            bias_c[g][r] = (b_ih[row] + b_hh[row]) * LOG2E;
        }
    }

    // zero h buffers (h0 = 0)
    for (int i = tid; i < 1024; i += NTHREADS)
        ((unsigned*)hbuf)[i] = 0u;

    // ---- x pointers (waves 0,1 handle t = 2*chunk + wv)
    const float* xp = x + ((size_t)(b0 + cm) * T_DIM + wv) * I_DIM + q * 8;
    const float* const xp_last = x + ((size_t)(b0 + cm) * T_DIM + (T_DIM - 1)) * I_DIM + q * 8;

    auto load_from = [&](const float* p, float4& xa, float4& xb) {
        xa = *(const float4*)p;
        if (q < 3) xb = *(const float4*)(p + 4);
        else       xb = float4{0.f, 0.f, 0.f, 0.f};   // I=28 pad to K=32
    };
    auto pack_store_x = [&](const float4& xa, const float4& xb) {
        u32x4 w;
        w[0] = pack_pair(xa.x, xa.y);
        w[1] = pack_pair(xa.z, xa.w);
        w[2] = pack_pair(xb.x, xb.y);
        w[3] = pack_pair(xb.z, xb.w);
        *(u32x4*)&xbuf[wv][lane * 4] = w;
    };

    // ---- prologue: xbuf <- x(chunk 0); xw_cur <- xw(chunk 0); prefetch x(chunk 1)
    float4 xa0{0,0,0,0}, xb0{0,0,0,0};
    if (wv < 2) { load_from(xp, xa0, xb0); pack_store_x(xa0, xb0); }
    __syncthreads();

    f32x4 xw_cur[2][4];
    #pragma unroll
    for (int tt = 0; tt < 2; ++tt) {
        bf16x8 X = __builtin_bit_cast(bf16x8, *(u32x4*)&xbuf[tt][lane * 4]);
        #pragma unroll
        for (int g = 0; g < 4; ++g) {
            f32x4 a = MFMA(Wih_hi[g], X, bias_c[g]);
            a = MFMA(Wih_lo[g], X, a);
            xw_cur[tt][g] = a;
        }
    }

    float4 xa_cur{0,0,0,0}, xb_cur{0,0,0,0};
    if (wv < 2) { xp += 2 * I_DIM; load_from(xp, xa_cur, xb_cur); }  // x(chunk 1)

    float2 c_st = {0.f, 0.f};   // scaled cell state (LOG2E*c), 2 cells/lane
    // h write dword: rows hb*16+4q+{0..3}, col cm; +1 dword for the r=2,3 wave
    const int hdw = 256 * (hb >> 1) + 64 * (2 * (hb & 1) + (q >> 1))
                  + 4 * cm + 2 * (q & 1) + (wv >> 2);

    #pragma unroll 2
    for (int ch = 0; ch < T_DIM / 2; ++ch) {
        // pack x(ch+1) into xbuf (loads issued last iteration)
        if (wv < 2) pack_store_x(xa_cur, xb_cur);
        BAR();   // xbuf(ch+1) visible; hbuf[0] writes from prev tt=1 visible

        // issue x(ch+2) load now; stays in flight across both barriers
        float4 xa_nxt{0,0,0,0}, xb_nxt{0,0,0,0};
        if (wv < 2) {
            const float* pn = (ch < T_DIM / 2 - 2) ? xp + 2 * I_DIM : xp_last;
            load_from(pn, xa_nxt, xb_nxt);
            xp = pn;
        }

        // X frags for xw(ch+1): read before the tt=1 barrier (disjoint from
        // next chunk's writes)
        bf16x8 X0 = __builtin_bit_cast(bf16x8, *(u32x4*)&xbuf[0][lane * 4]);
        bf16x8 X1 = __builtin_bit_cast(bf16x8, *(u32x4*)&xbuf[1][lane * 4]);

        f32x4 xw_nxt[2][4];
        #pragma unroll
        for (int tt = 0; tt < 2; ++tt) {
            const int rb = tt, wb = tt ^ 1;
            if (tt == 1) BAR();   // h(t) writes visible

            bf16x8 H0 = __builtin_bit_cast(bf16x8, *(u32x4*)&hbuf[rb][lane * 4]);
            bf16x8 H1 = __builtin_bit_cast(bf16x8, *(u32x4*)&hbuf[rb][256 + lane * 4]);

            // recurrence MFMAs (critical path) — duplicated by wave pairs
            f32x4 acc[4];
            #pragma unroll
            for (int g = 0; g < 4; ++g) {
                f32x4 a = MFMA(Whh[g][0], H0, xw_cur[tt][g]);
                a = MFMA(Whh[g][1], H1, a);
                acc[g] = a;
            }
            // xw(ch+1) for this tt: independent MFMAs under the activation chain
            bf16x8 X = (tt == 0) ? X0 : X1;
            #pragma unroll
            for (int g = 0; g < 4; ++g) {
                f32x4 a = MFMA(Wih_hi[g], X, bias_c[g]);
                a = MFMA(Wih_lo[g], X, a);
                xw_nxt[tt][g] = a;
            }

            // gather this wave's 2 cells with STATIC indices (uniform branch;
            // runtime-indexing an ext_vector would go to scratch)
            float gg[4][2];
            if (wv < 4) {
                #pragma unroll
                for (int g = 0; g < 4; ++g) { gg[g][0] = acc[g][0]; gg[g][1] = acc[g][1]; }
            } else {
                #pragma unroll
                for (int g = 0; g < 4; ++g) { gg[g][0] = acc[g][2]; gg[g][1] = acc[g][3]; }
            }

            // update 2 cells (half the activation VALU of the 4-wave version)
            float hh[2];
            #pragma unroll
            for (int r = 0; r < 2; ++r) {
                float ig = sigmoid_s(gg[0][r]);
                float fg = sigmoid_s(gg[1][r]);
                float gs = tanh_gs (gg[2][r]);
                float og = sigmoid_s(gg[3][r]);
                float cc = fmaf(fg, (r == 0) ? c_st.x : c_st.y, ig * gs);
                if (r == 0) c_st.x = cc; else c_st.y = cc;
                hh[r] = og * tanh_cs(cc);
            }
            hbuf[wb][hdw] = pack_pair(hh[0], hh[1]);
        }

        #pragma unroll
        for (int tt = 0; tt < 2; ++tt)
            #pragma unroll
            for (int g = 0; g < 4; ++g)
                xw_cur[tt][g] = xw_nxt[tt][g];
        xa_cur = xa_nxt; xb_cur = xb_nxt;
    }

    __syncthreads();   // full drain once; orders final hbuf[0] writes

    // ---- output head: final h(T) is in hbuf[0] (T even)
    if (tid < MB * OUT_DIM) {
        const int bb = tid / OUT_DIM;
        const int o  = tid % OUT_DIM;
        float s = b_out[o];
        const float* wo = W_out + o * H_DIM;
        #pragma unroll
        for (int u = 0; u < H_DIM; ++u) {
            const int dw = 256 * (u >> 5) + 64 * ((u >> 3) & 3) + 4 * bb + ((u >> 1) & 3);
            const int sh = (u & 1) * 16;
            float h = bfbits2f((hbuf[0][dw] >> sh) & 0xFFFFu);
            s += h * wo[u];
        }
        out[(size_t)(b0 + bb) * OUT_DIM + o] = s;
    }
}

extern "C" void kernel_launch(void* const* d_in, const int* in_sizes, int n_in,
                              void* d_out, int out_size, void* d_ws, size_t ws_size,
                              hipStream_t stream) {
    const float* x     = (const float*)d_in[0];
    const float* W_ih  = (const float*)d_in[1];
    const float* W_hh  = (const float*)d_in[2];
    const float* b_ih  = (const float*)d_in[3];
    const float* b_hh  = (const float*)d_in[4];
    const float* W_out = (const float*)d_in[5];
    const float* b_out = (const float*)d_in[6];
    float* out = (float*)d_out;

    dim3 grid(B_DIM / MB);    // 256 blocks -> 1 per CU
    dim3 block(NTHREADS);     // 8 waves -> 2 per SIMD (latency/pipe overlap)
    lstm_mfma_kernel<<<grid, block, 0, stream>>>(
        x, W_ih, W_hh, b_ih, b_hh, W_out, b_out, out);
}

// Round 4
// 151.432 us; speedup vs baseline: 1.1068x; 1.1068x over previous
//
#include <hip/hip_runtime.h>

#define I_DIM 28
#define H_DIM 64
#define T_DIM 128
#define B_DIM 4096
#define OUT_DIM 10
#define MB 16         // batch rows per block: full 16 MFMA B-columns
#define NTHREADS 256  // 4 waves; wave w owns gate-mtiles {w, w+4, w+8, w+12}
#define LOG2E 1.44269504088896340736f

typedef __attribute__((ext_vector_type(8))) short bf16x8;
typedef __attribute__((ext_vector_type(4))) float f32x4;
typedef __attribute__((ext_vector_type(4))) unsigned u32x4;

__device__ __forceinline__ float bfbits2f(unsigned b16) {
    return __builtin_bit_cast(float, b16 << 16);
}
// rne-rounded fp32 bits (bf16 lives in top 16 after the add)
__device__ __forceinline__ unsigned rne_u(float f) {
    unsigned u = __builtin_bit_cast(unsigned, f);
    return u + 0x7FFFu + ((u >> 16) & 1u);
}
// pack two floats -> (bf16(b)<<16)|bf16(a) : 2 rne-adds + 1 v_perm
__device__ __forceinline__ unsigned pack_pair(float a, float b) {
    return __builtin_amdgcn_perm(rne_u(b), rne_u(a), 0x07060302u);
}
__device__ __forceinline__ unsigned f2bf_rne(float f) { return rne_u(f) >> 16; }
__device__ __forceinline__ unsigned ftrunc_bf(float f) {
    return __builtin_bit_cast(unsigned, f) >> 16;
}

// 8 floats -> single rne-bf16 frag (4 dwords)
__device__ __forceinline__ bf16x8 pack_frag(const float* v) {
    u32x4 w;
    #pragma unroll
    for (int i = 0; i < 4; ++i) w[i] = pack_pair(v[2*i], v[2*i+1]);
    return __builtin_bit_cast(bf16x8, w);
}

// 8 floats -> hi/lo bf16 frags (used for W_ih only; startup)
__device__ __forceinline__ void split_frag(const float* v, bf16x8& hi, bf16x8& lo) {
    unsigned hb[8], lb[8];
    #pragma unroll
    for (int j = 0; j < 8; ++j) {
        hb[j] = f2bf_rne(v[j]);
        float rem = v[j] - bfbits2f(hb[j]);
        lb[j] = ftrunc_bf(rem);
    }
    u32x4 hw, lw;
    #pragma unroll
    for (int i = 0; i < 4; ++i) {
        hw[i] = (hb[2*i+1] << 16) | (hb[2*i] & 0xFFFFu);
        lw[i] = (lb[2*i+1] << 16) | (lb[2*i] & 0xFFFFu);
    }
    hi = __builtin_bit_cast(bf16x8, hw);
    lo = __builtin_bit_cast(bf16x8, lw);
}

__device__ __forceinline__ float fast_rcp(float v) { return __builtin_amdgcn_rcpf(v); }
__device__ __forceinline__ float exp2_f(float v)  { return __builtin_amdgcn_exp2f(v); }

// Merged-rcp LSTM cell update. All preacts LOG2E-scaled; cs is LOG2E*c.
// sigma(i)*tanh(g) = (C-1)/((1+A)(C+1)), A=e^-i, C=e^2g  -> 1 rcp not 2.
// sigma(o)*tanh(c) = (E-1)/((1+D)(E+1)), D=e^-o, E=e^2c  -> 1 rcp not 2.
// 5 exp + 3 rcp per cell (was 5+5). Inf-safe for |preact| < 44 (data: |z|<~6).
__device__ __forceinline__ float cell_update(float ia, float fa, float ga,
                                             float oa, float& cs) {
    float A  = exp2_f(-ia);
    float B  = exp2_f(-fa);
    float Cc = exp2_f(ga + ga);
    float D  = exp2_f(-oa);
    float fg = fast_rcp(1.0f + B);                       // sigma(f)
    float R1 = fast_rcp((1.0f + A) * (Cc + 1.0f));
    float P  = fmaf(Cc, LOG2E, -LOG2E) * R1;             // LOG2E*sig(i)*tanh(g)
    float cc = fmaf(fg, cs, P);
    cs = cc;
    float E  = exp2_f(cc + cc);
    float R2 = fast_rcp((1.0f + D) * (E + 1.0f));
    return (E - 1.0f) * R2;                              // h = sig(o)*tanh(c)
}

#define MFMA(A, B, C) __builtin_amdgcn_mfma_f32_16x16x32_bf16((A), (B), (C), 0, 0, 0)

// Raw barrier with counted wait: LDS writes must be visible (lgkmcnt(0)),
// but global loads (x prefetch) stay in flight across the barrier.
#define BAR() do {                                              \
    asm volatile("s_waitcnt lgkmcnt(0)" ::: "memory");          \
    __builtin_amdgcn_s_barrier();                               \
} while (0)

__global__ __launch_bounds__(NTHREADS, 1)
void lstm_mfma_kernel(const float* __restrict__ x,
                      const float* __restrict__ W_ih,
                      const float* __restrict__ W_hh,
                      const float* __restrict__ b_ih,
                      const float* __restrict__ b_hh,
                      const float* __restrict__ W_out,
                      const float* __restrict__ b_out,
                      float* __restrict__ out)
{
    const int tid  = threadIdx.x;
    const int wv   = tid >> 6;        // wave 0..3
    const int lane = tid & 63;
    const int q    = lane >> 4;       // quad
    const int cm   = lane & 15;       // batch column (all 16 real)
    const int b0   = blockIdx.x * MB;

    // h state, single rne-bf16, B-frag dword order, double-buffered.
    __shared__ __align__(16) unsigned hbuf[2][512];
    // x B-frags for the chunk's two timesteps (single bf16)
    __shared__ __align__(16) unsigned xbuf[2][256];

    // ---- resident A-frags (weights, pre-scaled by LOG2E):
    bf16x8 Whh[4][2], Wih_hi[4], Wih_lo[4];
    f32x4  bias_c[4];
    #pragma unroll
    for (int g = 0; g < 4; ++g) {
        const int gn = (wv + 4 * g) * 16 + cm;     // global gate row
        #pragma unroll
        for (int kt = 0; kt < 2; ++kt) {
            const float* wr = W_hh + gn * H_DIM + kt * 32 + q * 8;
            float wt[8];
            float4 wa = *(const float4*)wr;
            float4 wb = *(const float4*)(wr + 4);
            wt[0]=wa.x*LOG2E; wt[1]=wa.y*LOG2E; wt[2]=wa.z*LOG2E; wt[3]=wa.w*LOG2E;
            wt[4]=wb.x*LOG2E; wt[5]=wb.y*LOG2E; wt[6]=wb.z*LOG2E; wt[7]=wb.w*LOG2E;
            Whh[g][kt] = pack_frag(wt);
        }
        {
            const float* ir = W_ih + gn * I_DIM + q * 8;
            float wt[8];
            float4 ia = *(const float4*)ir;
            wt[0]=ia.x*LOG2E; wt[1]=ia.y*LOG2E; wt[2]=ia.z*LOG2E; wt[3]=ia.w*LOG2E;
            if (q < 3) {
                float4 ib = *(const float4*)(ir + 4);
                wt[4]=ib.x*LOG2E; wt[5]=ib.y*LOG2E; wt[6]=ib.z*LOG2E; wt[7]=ib.w*LOG2E;
            } else { wt[4]=0.f; wt[5]=0.f; wt[6]=0.f; wt[7]=0.f; }
            split_frag(wt, Wih_hi[g], Wih_lo[g]);
        }
        #pragma unroll
        for (int r = 0; r < 4; ++r) {
            const int row = g * H_DIM + wv * 16 + 4 * q + r;
            bias_c[g][r] = (b_ih[row] + b_hh[row]) * LOG2E;
        }
    }

    // zero h buffers (h0 = 0)
    for (int i = tid; i < 1024; i += NTHREADS)
        ((unsigned*)hbuf)[i] = 0u;

    // ---- symmetric x staging: ALL 4 waves stage; wave w covers timestep
    // (w>>1) of the chunk, half (w&1) of the 64 data-lanes; each lane does
    // one float4 load + 2 packs + 1 ds_write_b64 per chunk.
    const int tts = wv >> 1;              // staged timestep within chunk
    const int dl  = (wv & 1) * 32 + (lane & 31);  // data-lane 0..63
    const int ps  = lane >> 5;            // which dword pair of the frag
    const int sb  = dl & 15;              // staged batch
    const int qd  = dl >> 4;              // staged quad
    const int fo  = qd * 8 + ps * 4;      // float offset 0,4,...,28
    const bool sval = fo < I_DIM;         // fo==28 -> zero pad
    const float* xbase = x + (size_t)(b0 + sb) * T_DIM * I_DIM + fo;

    auto load_x4 = [&](int t) -> float4 {
        if (!sval) return float4{0.f, 0.f, 0.f, 0.f};
        return *(const float4*)(xbase + (size_t)t * I_DIM);
    };
    auto pack_store_x = [&](const float4& v) {
        uint2 pw;
        pw.x = pack_pair(v.x, v.y);
        pw.y = pack_pair(v.z, v.w);
        *(uint2*)&xbuf[tts][dl * 4 + 2 * ps] = pw;
    };

    // ---- prologue: xbuf <- x(chunk 0); xw_cur <- xw(chunk 0); xs <- x(chunk 1)
    pack_store_x(load_x4(tts));
    __syncthreads();

    f32x4 xwA[2][4], xwB[2][4];
    #pragma unroll
    for (int tt = 0; tt < 2; ++tt) {
        bf16x8 X = __builtin_bit_cast(bf16x8, *(u32x4*)&xbuf[tt][lane * 4]);
        #pragma unroll
        for (int g = 0; g < 4; ++g) {
            f32x4 a = MFMA(Wih_hi[g], X, bias_c[g]);
            a = MFMA(Wih_lo[g], X, a);
            xwA[tt][g] = a;
        }
    }

    float4 xs = load_x4(2 + tts);   // x(chunk 1)

    f32x4 c_st = {0.f, 0.f, 0.f, 0.f};   // scaled cell state, 4 cells/lane
    // h write dword: rows wv*16+4q+r, col cm -> b64 of two packed pairs
    const int hdw = 256 * (wv >> 1) + 64 * (2 * (wv & 1) + (q >> 1))
                  + 4 * cm + 2 * (q & 1);

    auto chunk_body = [&](int ch, f32x4 (&xwC)[2][4], f32x4 (&xwN)[2][4]) {
        // stage x(ch+1) into xbuf (regs loaded last chunk; vmcnt wait lands here)
        pack_store_x(xs);
        BAR();   // xbuf(ch+1) + prev tt=1 h writes visible

        // issue x(ch+2) load in the post-barrier LDS shadow
        int tld = 2 * ch + 4 + tts;
        if (tld > T_DIM - 1) tld = T_DIM - 1;
        float4 xs2 = load_x4(tld);

        // X frags for xw(ch+1): read before the tt=1 barrier (disjoint from
        // next chunk's writes, which happen after it)
        bf16x8 X0 = __builtin_bit_cast(bf16x8, *(u32x4*)&xbuf[0][lane * 4]);
        bf16x8 X1 = __builtin_bit_cast(bf16x8, *(u32x4*)&xbuf[1][lane * 4]);

        #pragma unroll
        for (int tt = 0; tt < 2; ++tt) {
            const int rb = tt, wb = tt ^ 1;
            if (tt == 1) BAR();   // h(t) writes visible

            bf16x8 H0 = __builtin_bit_cast(bf16x8, *(u32x4*)&hbuf[rb][lane * 4]);
            bf16x8 H1 = __builtin_bit_cast(bf16x8, *(u32x4*)&hbuf[rb][256 + lane * 4]);

            // recurrence MFMAs (critical path)
            f32x4 acc[4];
            #pragma unroll
            for (int g = 0; g < 4; ++g) {
                f32x4 a = MFMA(Whh[g][0], H0, xwC[tt][g]);
                a = MFMA(Whh[g][1], H1, a);
                acc[g] = a;
            }
            // xw(ch+1): independent MFMAs fill the pipe under the activations
            bf16x8 X = (tt == 0) ? X0 : X1;
            #pragma unroll
            for (int g = 0; g < 4; ++g) {
                f32x4 a = MFMA(Wih_hi[g], X, bias_c[g]);
                a = MFMA(Wih_lo[g], X, a);
                xwN[tt][g] = a;
            }

            // update 4 cells (merged-rcp: 5 exp + 3 rcp per cell)
            float hh[4];
            #pragma unroll
            for (int r = 0; r < 4; ++r) {
                float csr = c_st[r];
                hh[r] = cell_update(acc[0][r], acc[1][r], acc[2][r], acc[3][r], csr);
                c_st[r] = csr;
            }
            uint2 hw2;
            hw2.x = pack_pair(hh[0], hh[1]);
            hw2.y = pack_pair(hh[2], hh[3]);
            *(uint2*)&hbuf[wb][hdw] = hw2;
        }
        xs = xs2;
    };

    for (int ch = 0; ch < T_DIM / 2; ch += 2) {
        chunk_body(ch,     xwA, xwB);   // ping-pong: no xw copy movs
        chunk_body(ch + 1, xwB, xwA);
    }

    __syncthreads();   // full drain; orders final hbuf[0] writes

    // ---- output head: final h(T) is in hbuf[0] (T even)
    if (tid < MB * OUT_DIM) {
        const int bb = tid / OUT_DIM;
        const int o  = tid % OUT_DIM;
        float s = b_out[o];
        const float* wo = W_out + o * H_DIM;
        #pragma unroll
        for (int u = 0; u < H_DIM; ++u) {
            const int dw = 256 * (u >> 5) + 64 * ((u >> 3) & 3) + 4 * bb + ((u >> 1) & 3);
            const int sh = (u & 1) * 16;
            float h = bfbits2f((hbuf[0][dw] >> sh) & 0xFFFFu);
            s += h * wo[u];
        }
        out[(size_t)(b0 + bb) * OUT_DIM + o] = s;
    }
}

extern "C" void kernel_launch(void* const* d_in, const int* in_sizes, int n_in,
                              void* d_out, int out_size, void* d_ws, size_t ws_size,
                              hipStream_t stream) {
    const float* x     = (const float*)d_in[0];
    const float* W_ih  = (const float*)d_in[1];
    const float* W_hh  = (const float*)d_in[2];
    const float* b_ih  = (const float*)d_in[3];
    const float* b_hh  = (const float*)d_in[4];
    const float* W_out = (const float*)d_in[5];
    const float* b_out = (const float*)d_in[6];
    float* out = (float*)d_out;

    dim3 grid(B_DIM / MB);    // 256 blocks -> 1 per CU, full 16-col MFMAs
    dim3 block(NTHREADS);     // 4 waves (1 per SIMD)
    lstm_mfma_kernel<<<grid, block, 0, stream>>>(
        x, W_ih, W_hh, b_ih, b_hh, W_out, b_out, out);
}

// Round 5
// 145.460 us; speedup vs baseline: 1.1523x; 1.0411x over previous
//
#include <hip/hip_runtime.h>

#define I_DIM 28
#define H_DIM 64
#define T_DIM 128
#define B_DIM 4096
#define OUT_DIM 10
#define MB 16         // batch rows per block: full 16 MFMA B-columns
#define NTHREADS 512  // 8 waves: 0-3 critical (recurrence+acts), 4-7 helper
                      // (x staging + xw=W_ih*x+b one chunk ahead, via LDS)
#define LOG2E 1.44269504088896340736f

typedef __attribute__((ext_vector_type(8))) short bf16x8;
typedef __attribute__((ext_vector_type(4))) float f32x4;
typedef __attribute__((ext_vector_type(4))) unsigned u32x4;

__device__ __forceinline__ float bfbits2f(unsigned b16) {
    return __builtin_bit_cast(float, b16 << 16);
}
// rne-rounded fp32 bits (bf16 lives in top 16 after the add)
__device__ __forceinline__ unsigned rne_u(float f) {
    unsigned u = __builtin_bit_cast(unsigned, f);
    return u + 0x7FFFu + ((u >> 16) & 1u);
}
// pack two floats -> (bf16(b)<<16)|bf16(a) : 2 rne-adds + 1 v_perm
__device__ __forceinline__ unsigned pack_pair(float a, float b) {
    return __builtin_amdgcn_perm(rne_u(b), rne_u(a), 0x07060302u);
}
__device__ __forceinline__ unsigned f2bf_rne(float f) { return rne_u(f) >> 16; }
__device__ __forceinline__ unsigned ftrunc_bf(float f) {
    return __builtin_bit_cast(unsigned, f) >> 16;
}

// 8 floats -> single rne-bf16 frag (4 dwords)
__device__ __forceinline__ bf16x8 pack_frag(const float* v) {
    u32x4 w;
    #pragma unroll
    for (int i = 0; i < 4; ++i) w[i] = pack_pair(v[2*i], v[2*i+1]);
    return __builtin_bit_cast(bf16x8, w);
}

// 8 floats -> hi/lo bf16 frags (used for W_ih only; startup)
__device__ __forceinline__ void split_frag(const float* v, bf16x8& hi, bf16x8& lo) {
    unsigned hb[8], lb[8];
    #pragma unroll
    for (int j = 0; j < 8; ++j) {
        hb[j] = f2bf_rne(v[j]);
        float rem = v[j] - bfbits2f(hb[j]);
        lb[j] = ftrunc_bf(rem);
    }
    u32x4 hw, lw;
    #pragma unroll
    for (int i = 0; i < 4; ++i) {
        hw[i] = (hb[2*i+1] << 16) | (hb[2*i] & 0xFFFFu);
        lw[i] = (lb[2*i+1] << 16) | (lb[2*i] & 0xFFFFu);
    }
    hi = __builtin_bit_cast(bf16x8, hw);
    lo = __builtin_bit_cast(bf16x8, lw);
}

__device__ __forceinline__ float fast_rcp(float v) { return __builtin_amdgcn_rcpf(v); }
__device__ __forceinline__ float exp2_f(float v)  { return __builtin_amdgcn_exp2f(v); }

// Merged-rcp LSTM cell update. All preacts LOG2E-scaled; cs is LOG2E*c.
// sigma(i)*tanh(g) = (C-1)/((1+A)(C+1)), A=e^-i, C=e^2g  -> 1 rcp not 2.
// sigma(o)*tanh(c) = (E-1)/((1+D)(E+1)), D=e^-o, E=e^2c  -> 1 rcp not 2.
// 5 exp + 3 rcp per cell. Inf-safe for |preact| < 44 (data: |z| < ~6).
__device__ __forceinline__ float cell_update(float ia, float fa, float ga,
                                             float oa, float& cs) {
    float A  = exp2_f(-ia);
    float B  = exp2_f(-fa);
    float Cc = exp2_f(ga + ga);
    float D  = exp2_f(-oa);
    float fg = fast_rcp(1.0f + B);                       // sigma(f)
    float R1 = fast_rcp((1.0f + A) * (Cc + 1.0f));
    float P  = fmaf(Cc, LOG2E, -LOG2E) * R1;             // LOG2E*sig(i)*tanh(g)
    float cc = fmaf(fg, cs, P);
    cs = cc;
    float E  = exp2_f(cc + cc);
    float R2 = fast_rcp((1.0f + D) * (E + 1.0f));
    return (E - 1.0f) * R2;                              // h = sig(o)*tanh(c)
}

#define MFMA(A, B, C) __builtin_amdgcn_mfma_f32_16x16x32_bf16((A), (B), (C), 0, 0, 0)

// Raw barrier with counted wait: LDS writes must be visible (lgkmcnt(0)),
// but global loads (helper x prefetch) stay in flight across the barrier.
#define BAR() do {                                              \
    asm volatile("s_waitcnt lgkmcnt(0)" ::: "memory");          \
    __builtin_amdgcn_s_barrier();                               \
} while (0)

__global__ __launch_bounds__(NTHREADS, 1)
void lstm_mfma_kernel(const float* __restrict__ x,
                      const float* __restrict__ W_ih,
                      const float* __restrict__ W_hh,
                      const float* __restrict__ b_ih,
                      const float* __restrict__ b_hh,
                      const float* __restrict__ W_out,
                      const float* __restrict__ b_out,
                      float* __restrict__ out)
{
    const int tid  = threadIdx.x;
    const int wv   = tid >> 6;        // wave 0..7
    const int rw   = wv & 3;          // role-local wave index 0..3
    const bool helper = wv >= 4;
    const int lane = tid & 63;
    const int q    = lane >> 4;       // quad
    const int cm   = lane & 15;       // batch column (all 16 real)
    const int b0   = blockIdx.x * MB;

    // h state, single rne-bf16, B-frag dword order, double-buffered (4 KB)
    __shared__ __align__(16) unsigned hbuf[2][512];
    // x B-frags, [chunk parity][tt][frag dwords] (8 KB); helpers only
    __shared__ __align__(16) unsigned xbuf[2][2][256];
    // xw = W_ih*x + b, f32 C-frags: [chunk parity][tt][gate][(rw*64+lane)*4] (64 KB)
    __shared__ __align__(16) float    xwbuf[2][2][4][1024];

    // ---- resident A-frags (weights, pre-scaled by LOG2E), per role:
    bf16x8 Whh[4][2];                 // critical
    bf16x8 Wih_hi[4], Wih_lo[4];      // helper
    f32x4  bias_c[4];                 // helper
    if (!helper) {
        #pragma unroll
        for (int g = 0; g < 4; ++g) {
            const int gn = (rw + 4 * g) * 16 + cm;     // global gate row
            #pragma unroll
            for (int kt = 0; kt < 2; ++kt) {
                const float* wr = W_hh + gn * H_DIM + kt * 32 + q * 8;
                float wt[8];
                float4 wa = *(const float4*)wr;
                float4 wb = *(const float4*)(wr + 4);
                wt[0]=wa.x*LOG2E; wt[1]=wa.y*LOG2E; wt[2]=wa.z*LOG2E; wt[3]=wa.w*LOG2E;
                wt[4]=wb.x*LOG2E; wt[5]=wb.y*LOG2E; wt[6]=wb.z*LOG2E; wt[7]=wb.w*LOG2E;
                Whh[g][kt] = pack_frag(wt);
            }
        }
    } else {
        #pragma unroll
        for (int g = 0; g < 4; ++g) {
            const int gn = (rw + 4 * g) * 16 + cm;
            const float* ir = W_ih + gn * I_DIM + q * 8;
            float wt[8];
            float4 ia = *(const float4*)ir;
            wt[0]=ia.x*LOG2E; wt[1]=ia.y*LOG2E; wt[2]=ia.z*LOG2E; wt[3]=ia.w*LOG2E;
            if (q < 3) {
                float4 ib = *(const float4*)(ir + 4);
                wt[4]=ib.x*LOG2E; wt[5]=ib.y*LOG2E; wt[6]=ib.z*LOG2E; wt[7]=ib.w*LOG2E;
            } else { wt[4]=0.f; wt[5]=0.f; wt[6]=0.f; wt[7]=0.f; }
            split_frag(wt, Wih_hi[g], Wih_lo[g]);
            #pragma unroll
            for (int r = 0; r < 4; ++r) {
                const int row = g * H_DIM + rw * 16 + 4 * q + r;
                bias_c[g][r] = (b_ih[row] + b_hh[row]) * LOG2E;
            }
        }
    }

    // zero h buffers (h0 = 0)
    for (int i = tid; i < 1024; i += NTHREADS)
        ((unsigned*)hbuf)[i] = 0u;

    // ---- helper staging geometry: helper rw covers timestep (rw>>1) of the
    // chunk, half (rw&1) of the 64 data-lanes; one float4 load + 2 packs +
    // 1 ds_write_b64 per chunk per lane.
    const int tts = rw >> 1;
    const int dl  = (rw & 1) * 32 + (lane & 31);  // data-lane 0..63
    const int ps  = lane >> 5;
    const int fo  = (dl >> 4) * 8 + ps * 4;       // float offset 0..28
    const bool sval = fo < I_DIM;                 // fo==28 -> zero pad
    const float* xbase = x + (size_t)(b0 + (dl & 15)) * T_DIM * I_DIM + fo;

    auto load_x4 = [&](int t) -> float4 {
        if (!sval) return float4{0.f, 0.f, 0.f, 0.f};
        return *(const float4*)(xbase + (size_t)t * I_DIM);
    };
    auto pack_store_x = [&](int slot, const float4& v) {
        uint2 pw;
        pw.x = pack_pair(v.x, v.y);
        pw.y = pack_pair(v.z, v.w);
        *(uint2*)&xbuf[slot][tts][dl * 4 + 2 * ps] = pw;
    };

    const int xwt = (rw * 64 + lane) * 4;   // float offset into xwbuf[..][g]

    // ---- prologue: xbuf[0]=x(ch0), xbuf[1]=x(ch1); xw(ch0)->xwbuf[0];
    // xs regs <- x(ch2)
    if (helper) {
        pack_store_x(0, load_x4(tts));
        pack_store_x(1, load_x4(2 + tts));
    }
    __syncthreads();
    float4 xs{0.f, 0.f, 0.f, 0.f};
    if (helper) {
        #pragma unroll
        for (int tt = 0; tt < 2; ++tt) {
            bf16x8 X = __builtin_bit_cast(bf16x8, *(const u32x4*)&xbuf[0][tt][lane * 4]);
            #pragma unroll
            for (int g = 0; g < 4; ++g) {
                f32x4 a = MFMA(Wih_hi[g], X, bias_c[g]);
                a = MFMA(Wih_lo[g], X, a);
                *(f32x4*)&xwbuf[0][tt][g][xwt] = a;
            }
        }
        xs = load_x4(4 + tts);   // x(chunk 2)
    }
    __syncthreads();

    f32x4 c_st = {0.f, 0.f, 0.f, 0.f};   // scaled cell state, 4 cells/lane
    // h write dword: rows rw*16+4q+r, col cm -> b64 of two packed pairs
    const int hdw = 256 * (rw >> 1) + 64 * (2 * (rw & 1) + (q >> 1))
                  + 4 * cm + 2 * (q & 1);

    auto rec_step = [&](const unsigned* hrd, unsigned* hwr, const f32x4* xw) {
        bf16x8 H0 = __builtin_bit_cast(bf16x8, *(const u32x4*)&hrd[lane * 4]);
        bf16x8 H1 = __builtin_bit_cast(bf16x8, *(const u32x4*)&hrd[256 + lane * 4]);
        f32x4 acc[4];
        #pragma unroll
        for (int g = 0; g < 4; ++g) {
            f32x4 a = MFMA(Whh[g][0], H0, xw[g]);
            a = MFMA(Whh[g][1], H1, a);
            acc[g] = a;
        }
        float hh[4];
        #pragma unroll
        for (int r = 0; r < 4; ++r) {
            float csr = c_st[r];
            hh[r] = cell_update(acc[0][r], acc[1][r], acc[2][r], acc[3][r], csr);
            c_st[r] = csr;
        }
        uint2 hw2;
        hw2.x = pack_pair(hh[0], hh[1]);
        hw2.y = pack_pair(hh[2], hh[3]);
        *(uint2*)&hwr[hdw] = hw2;
    };

    if (!helper) __builtin_amdgcn_s_setprio(1);   // critical wave = long pole

    for (int ch = 0; ch < T_DIM / 2; ++ch) {
        const int p = ch & 1;
        // helper: xbuf[p] <- x(ch+2) (xs regs loaded a chunk ago; the vmcnt
        // wait lands here, long after issue)
        if (helper) pack_store_x(p, xs);
        BAR();   // xw(ch) in xwbuf[p], xbuf writes, prev h writes all visible

        if (!helper) {
            // ---- critical: pure recurrence
            f32x4 xw0[4], xw1[4];
            #pragma unroll
            for (int g = 0; g < 4; ++g)
                xw0[g] = *(const f32x4*)&xwbuf[p][0][g][xwt];
            #pragma unroll
            for (int g = 0; g < 4; ++g)
                xw1[g] = *(const f32x4*)&xwbuf[p][1][g][xwt];
            rec_step(hbuf[0], hbuf[1], xw0);
            BAR();   // h(t) visible
            rec_step(hbuf[1], hbuf[0], xw1);
        } else {
            // ---- helper: xw(ch+1) from xbuf[p^1], written into xwbuf[p^1]
            bf16x8 X0 = __builtin_bit_cast(bf16x8, *(const u32x4*)&xbuf[p ^ 1][0][lane * 4]);
            bf16x8 X1 = __builtin_bit_cast(bf16x8, *(const u32x4*)&xbuf[p ^ 1][1][lane * 4]);
            #pragma unroll
            for (int g = 0; g < 4; ++g) {
                f32x4 a = MFMA(Wih_hi[g], X0, bias_c[g]);
                a = MFMA(Wih_lo[g], X0, a);
                *(f32x4*)&xwbuf[p ^ 1][0][g][xwt] = a;
            }
            int tld = 2 * ch + 6 + tts;          // x for chunk ch+3
            if (tld > T_DIM - 1) tld = T_DIM - 1;
            float4 xs2 = load_x4(tld);
            BAR();   // matches critical's mid-chunk barrier
            #pragma unroll
            for (int g = 0; g < 4; ++g) {
                f32x4 a = MFMA(Wih_hi[g], X1, bias_c[g]);
                a = MFMA(Wih_lo[g], X1, a);
                *(f32x4*)&xwbuf[p ^ 1][1][g][xwt] = a;
            }
            xs = xs2;
        }
    }
    if (!helper) __builtin_amdgcn_s_setprio(0);

    __syncthreads();   // full drain; orders final hbuf[0] writes

    // ---- output head: final h(T) is in hbuf[0] (T even)
    if (tid < MB * OUT_DIM) {
        const int bb = tid / OUT_DIM;
        const int o  = tid % OUT_DIM;
        float s = b_out[o];
        const float* wo = W_out + o * H_DIM;
        #pragma unroll
        for (int u = 0; u < H_DIM; ++u) {
            const int dw = 256 * (u >> 5) + 64 * ((u >> 3) & 3) + 4 * bb + ((u >> 1) & 3);
            const int sh = (u & 1) * 16;
            float h = bfbits2f((hbuf[0][dw] >> sh) & 0xFFFFu);
            s += h * wo[u];
        }
        out[(size_t)(b0 + bb) * OUT_DIM + o] = s;
    }
}

extern "C" void kernel_launch(void* const* d_in, const int* in_sizes, int n_in,
                              void* d_out, int out_size, void* d_ws, size_t ws_size,
                              hipStream_t stream) {
    const float* x     = (const float*)d_in[0];
    const float* W_ih  = (const float*)d_in[1];
    const float* W_hh  = (const float*)d_in[2];
    const float* b_ih  = (const float*)d_in[3];
    const float* b_hh  = (const float*)d_in[4];
    const float* W_out = (const float*)d_in[5];
    const float* b_out = (const float*)d_in[6];
    float* out = (float*)d_out;

    dim3 grid(B_DIM / MB);    // 256 blocks -> 1 per CU
    dim3 block(NTHREADS);     // 8 waves: 4 critical + 4 helper (2/SIMD, antiphase)
    lstm_mfma_kernel<<<grid, block, 0, stream>>>(
        x, W_ih, W_hh, b_ih, b_hh, W_out, b_out, out);
}